// Round 9
// baseline (204.052 us; speedup 1.0000x reference)
//
#include <hip/hip_runtime.h>
#include <hip/hip_fp16.h>
#include <math.h>

// Problem constants (from reference)
#define NN 20000          // nodes
#define TT 4              // time steps
#define EE 320000         // edges
#define NT (NN*TT)        // 80000 rows
#define H1 8              // heads layer 1
#define C1 128            // heads*f_out layer 1
#define IN_F 32
#define OUT_F 16
#define CAP 96            // bucket capacity; max degree Poisson(16) << 96
#define SCAT_BLOCKS 313   // ceil((EE/4)/256)
#define FEAT1_BLOCKS 1250 // NT/64

typedef _Float16 h8 __attribute__((ext_vector_type(8)));
typedef _Float16 h4v __attribute__((ext_vector_type(4)));
typedef float f32x4 __attribute__((ext_vector_type(4)));
typedef int i4v __attribute__((ext_vector_type(4)));

__device__ __forceinline__ float lrelu_exp(float e) {
  e = (e >= 0.f) ? e : 0.2f * e;
  return __expf(e);
}

// ---------------------------------------------------------------------------
// K1 "front": blocks 0..312 = bucket-CSR scatter (start first: longer pole);
// blocks 313.. = feat1 MFMA GEMM with per-block LDS W1p build.
// ---------------------------------------------------------------------------
__global__ __launch_bounds__(256) void k_front(
    const float* __restrict__ x, const float* __restrict__ W1,
    const float* __restrict__ al1, const float* __restrict__ ar1,
    const int4* __restrict__ src4, const int4* __restrict__ dst4,
    int* __restrict__ cnt, int* __restrict__ csr96,
    __half* __restrict__ feat1h, float* __restrict__ el1,
    float* __restrict__ er1) {
  __shared__ h8 W1ps[9 * 64];            // 9.2 KB, feat1 branch only
  int b = blockIdx.x;
  int tid = threadIdx.x;
  if (b < SCAT_BLOCKS) {
    int e4 = b * 256 + tid;
    if (e4 < EE / 4) {
      int4 s = src4[e4];
      int4 d = dst4[e4];
      int p0 = atomicAdd(&cnt[d.x], 1); csr96[d.x * CAP + p0] = s.x;
      int p1 = atomicAdd(&cnt[d.y], 1); csr96[d.y * CAP + p1] = s.y;
      int p2 = atomicAdd(&cnt[d.z], 1); csr96[d.z * CAP + p2] = s.z;
      int p3 = atomicAdd(&cnt[d.w], 1); csr96[d.w * CAP + p3] = s.w;
    }
    return;
  }
  // ---- feat1 branch ----
  __half* W1p = (__half*)W1ps;
  for (int idx = tid; idx < 9 * 512; idx += 256) {
    int tile = idx >> 9;
    int rem = idx & 511;
    int lane = rem >> 3, j = rem & 7;
    int k = (lane >> 4) * 8 + j;
    int n = lane & 15;
    float v;
    if (tile < 8) {
      v = W1[k * C1 + tile * 16 + n];
    } else {
      int hh_ = n & 7;
      const float* a = (n < 8) ? al1 : ar1;
      float s = 0.f;
      for (int f = 0; f < 16; ++f) s += W1[k * C1 + hh_ * 16 + f] * a[hh_ * 16 + f];
      v = s;
    }
    W1p[idx] = __float2half(v);
  }
  __syncthreads();
  int wave = tid >> 6, lane = tid & 63;
  int m = lane & 15, quad = lane >> 4;
  int rowbase = (b - SCAT_BLOCKS) * 64 + wave * 16;
  int row = rowbase + m;
  const float4* xp = (const float4*)(x + row * IN_F + quad * 8);
  float4 a0 = xp[0], a1 = xp[1];
  h8 af;
  af[0] = (_Float16)a0.x; af[1] = (_Float16)a0.y;
  af[2] = (_Float16)a0.z; af[3] = (_Float16)a0.w;
  af[4] = (_Float16)a1.x; af[5] = (_Float16)a1.y;
  af[6] = (_Float16)a1.z; af[7] = (_Float16)a1.w;
#pragma unroll
  for (int ht = 0; ht < 8; ++ht) {
    h8 bf = W1ps[ht * 64 + lane];
    f32x4 c = {0.f, 0.f, 0.f, 0.f};
    c = __builtin_amdgcn_mfma_f32_16x16x32_f16(af, bf, c, 0, 0, 0);
#pragma unroll
    for (int r = 0; r < 4; ++r)
      feat1h[(size_t)(rowbase + quad * 4 + r) * C1 + ht * 16 + m] = __float2half(c[r]);
  }
  {
    h8 bf = W1ps[8 * 64 + lane];
    f32x4 c = {0.f, 0.f, 0.f, 0.f};
    c = __builtin_amdgcn_mfma_f32_16x16x32_f16(af, bf, c, 0, 0, 0);
#pragma unroll
    for (int r = 0; r < 4; ++r) {
      int orow = rowbase + quad * 4 + r;
      if (m < 8) el1[orow * H1 + m] = c[r];
      else       er1[orow * H1 + (m - 8)] = c[r];
    }
  }
}

// ---------------------------------------------------------------------------
// K2: layer-1 softmax-aggregate (one wave per node, all 4 t, 8-edge SW
// pipeline) + FUSED feat2: the wave's h output is shfl-transposed into MFMA
// A-layout and multiplied against an LDS-built W2p (feat tiles + el2/er2
// tiles). No hh global round trip, no separate feat2 launch.
// ---------------------------------------------------------------------------
__global__ __launch_bounds__(256) void k_agg1f(
    const __half* __restrict__ feat1h,   // [n*4+t][128]
    const float* __restrict__ el1,       // [n][32] = [n][t][8]
    const float* __restrict__ er1,
    const int* __restrict__ cnt, const int* __restrict__ csr96,
    const float* __restrict__ b1,
    const float* __restrict__ W2, const float* __restrict__ al2,
    const float* __restrict__ ar2,
    __half* __restrict__ feat2h, float* __restrict__ el2,
    float* __restrict__ er2) {
  __shared__ h8 W2ps[8 * 64];            // 8 KB
  int tid = threadIdx.x;
  {
    __half* W2p = (__half*)W2ps;
    for (int idx = tid; idx < 8 * 512; idx += 256) {
      int tile = idx >> 9;
      int rem = idx & 511;
      int lane = rem >> 3, j = rem & 7;
      int ks = tile & 3;
      int k = ks * 32 + (lane >> 4) * 8 + j;
      int n = lane & 15;
      float v = 0.f;
      if (tile < 4) {
        v = W2[k * OUT_F + n];
      } else if (n == 0) {
        float s = 0.f;
        for (int f = 0; f < 16; ++f) s += W2[k * OUT_F + f] * al2[f];
        v = s;
      } else if (n == 1) {
        float s = 0.f;
        for (int f = 0; f < 16; ++f) s += W2[k * OUT_F + f] * ar2[f];
        v = s;
      }
      W2p[idx] = __float2half(v);
    }
  }
  __syncthreads();

  int wv = tid >> 6, lane = tid & 63;
  int n = blockIdx.x * 4 + wv;
  int ci = lane & 15;
  int i32 = lane & 31;                       // (t,h) slot this lane computes
  int src_lane = ((lane >> 4) << 3) + (ci >> 1);  // t*8 + hh
  float er_i = er1[(size_t)n * 32 + i32];
  int deg = cnt[n];
  const int* eb = csr96 + (size_t)n * CAP;
  float acc[8];
#pragma unroll
  for (int k = 0; k < 8; ++k) acc[k] = 0.f;
  float l = 0.f;
  for (int chunk = 0; chunk < deg; chunk += 64) {
    int m = min(64, deg - chunk);
    int sv = (lane < m) ? eb[chunk + lane] : 0;
    int iters = (m + 7) >> 3;
    for (int g = 0; g < iters; ++g) {
      int j = g * 8;
      int s0 = __builtin_amdgcn_readlane(sv, j + 0);
      int s1 = __builtin_amdgcn_readlane(sv, j + 1);
      int s2 = __builtin_amdgcn_readlane(sv, j + 2);
      int s3 = __builtin_amdgcn_readlane(sv, j + 3);
      int s4 = __builtin_amdgcn_readlane(sv, j + 4);
      int s5 = __builtin_amdgcn_readlane(sv, j + 5);
      int s6 = __builtin_amdgcn_readlane(sv, j + 6);
      int s7 = __builtin_amdgcn_readlane(sv, j + 7);
      float ew0 = el1[(size_t)s0 * 32 + i32];
      float ew1 = el1[(size_t)s1 * 32 + i32];
      float ew2 = el1[(size_t)s2 * 32 + i32];
      float ew3 = el1[(size_t)s3 * 32 + i32];
      float ew4 = el1[(size_t)s4 * 32 + i32];
      float ew5 = el1[(size_t)s5 * 32 + i32];
      float ew6 = el1[(size_t)s6 * 32 + i32];
      float ew7 = el1[(size_t)s7 * 32 + i32];
      h8 f0 = *(const h8*)(feat1h + (size_t)s0 * 512 + lane * 8);
      h8 f1 = *(const h8*)(feat1h + (size_t)s1 * 512 + lane * 8);
      h8 f2 = *(const h8*)(feat1h + (size_t)s2 * 512 + lane * 8);
      h8 f3 = *(const h8*)(feat1h + (size_t)s3 * 512 + lane * 8);
      h8 f4 = *(const h8*)(feat1h + (size_t)s4 * 512 + lane * 8);
      h8 f5 = *(const h8*)(feat1h + (size_t)s5 * 512 + lane * 8);
      h8 f6 = *(const h8*)(feat1h + (size_t)s6 * 512 + lane * 8);
      h8 f7 = *(const h8*)(feat1h + (size_t)s7 * 512 + lane * 8);
#define CONSUME(K, EW, F)                                         \
      {                                                           \
        float w_ = lrelu_exp(EW + er_i);                          \
        w_ = (j + K < m) ? w_ : 0.f;                              \
        float wb_ = __shfl(w_, src_lane);                         \
        l += wb_;                                                 \
        _Pragma("unroll")                                         \
        for (int q = 0; q < 8; ++q)                               \
          acc[q] = fmaf(wb_, (float)F[q], acc[q]);                \
      }
      CONSUME(0, ew0, f0) CONSUME(1, ew1, f1)
      CONSUME(2, ew2, f2) CONSUME(3, ew3, f3)
      CONSUME(4, ew4, f4) CONSUME(5, ew5, f5)
      CONSUME(6, ew6, f6) CONSUME(7, ew7, f7)
#undef CONSUME
    }
  }
  float inv = (l > 0.f) ? (1.f / l) : 0.f;
  float4 bv0 = *(const float4*)&b1[ci * 8];
  float4 bv1 = *(const float4*)&b1[ci * 8 + 4];
  h8 r;
  r[0] = (_Float16)(acc[0] * inv + bv0.x);
  r[1] = (_Float16)(acc[1] * inv + bv0.y);
  r[2] = (_Float16)(acc[2] * inv + bv0.z);
  r[3] = (_Float16)(acc[3] * inv + bv0.w);
  r[4] = (_Float16)(acc[4] * inv + bv1.x);
  r[5] = (_Float16)(acc[5] * inv + bv1.y);
  r[6] = (_Float16)(acc[6] * inv + bv1.z);
  r[7] = (_Float16)(acc[7] * inv + bv1.w);

  // ---- fused feat2 tail ----
  // h row t, channels 8*ci.. live in lane t*16+ci as r. A-frag for MFMA
  // needs lane (m, quad) to hold channels ks*32+quad*8..+7 of row m:
  // source lane = m*16 + ks*4 + quad (valid rows m<4; others garbage-pad).
  union U { h8 v; i4v d; };
  U u; u.v = r;
  int m = lane & 15, quad = lane >> 4;
  f32x4 cF = {0.f, 0.f, 0.f, 0.f};
  f32x4 cE = {0.f, 0.f, 0.f, 0.f};
#pragma unroll
  for (int ks = 0; ks < 4; ++ks) {
    int srcl = (m * 16 + ks * 4 + quad) & 63;
    U a;
#pragma unroll
    for (int q = 0; q < 4; ++q) a.d[q] = __shfl(u.d[q], srcl);
    cF = __builtin_amdgcn_mfma_f32_16x16x32_f16(a.v, W2ps[ks * 64 + lane], cF, 0, 0, 0);
    cE = __builtin_amdgcn_mfma_f32_16x16x32_f16(a.v, W2ps[(4 + ks) * 64 + lane], cE, 0, 0, 0);
  }
  if (quad == 0) {                       // lanes 0..15 hold rows 0..3, col=m
#pragma unroll
    for (int rr = 0; rr < 4; ++rr)
      feat2h[(size_t)(n * 4 + rr) * OUT_F + m] = __float2half(cF[rr]);
    if (m == 0) {
      float4 v = {cE[0], cE[1], cE[2], cE[3]};
      *(float4*)&el2[n * 4] = v;
    }
    if (m == 1) {
      float4 v = {cE[0], cE[1], cE[2], cE[3]};
      *(float4*)&er2[n * 4] = v;
    }
  }
}

// ---------------------------------------------------------------------------
// K3: layer-2 aggregate. One wave per node; 4 edges per iteration
// (16 lanes/edge, one 8B h4 load each). Weights in wave-private LDS with
// stride-5 padding; butterfly-reduce over the 4 edge-slots at the end.
// ---------------------------------------------------------------------------
__global__ __launch_bounds__(256) void k_agg2(
    const __half* __restrict__ feat2h,     // [n*4+t][16]
    const float* __restrict__ el2, const float* __restrict__ er2,  // [n*4+t]
    const int* __restrict__ cnt, const int* __restrict__ csr96,
    const float* __restrict__ b2, float* __restrict__ out) {
  __shared__ float myp[4][64][5];          // stride-5 pad: conflict-free
  __shared__ int   svs[4][64];
  int tid = threadIdx.x;
  int wv = tid >> 6, lane = tid & 63;
  int n = blockIdx.x * 4 + wv;
  int e4 = lane >> 4, sub = lane & 15;
  int t = sub >> 2, fq = sub & 3;          // 4 channels fq*4..fq*4+3
  int deg = cnt[n];
  const int* eb = csr96 + (size_t)n * CAP;
  float4 ern = *(const float4*)&er2[n * TT];
  float acc[4] = {0.f, 0.f, 0.f, 0.f};
  float l = 0.f;
  for (int chunk = 0; chunk < deg; chunk += 64) {
    int m = min(64, deg - chunk);
    float4 w = {0.f, 0.f, 0.f, 0.f};
    int s = 0;
    if (lane < m) {
      s = eb[chunk + lane];
      float4 e = *(const float4*)&el2[s * TT];
      w.x = lrelu_exp(e.x + ern.x);
      w.y = lrelu_exp(e.y + ern.y);
      w.z = lrelu_exp(e.z + ern.z);
      w.w = lrelu_exp(e.w + ern.w);
    }
    svs[wv][lane] = s;
    myp[wv][lane][0] = w.x;
    myp[wv][lane][1] = w.y;
    myp[wv][lane][2] = w.z;
    myp[wv][lane][3] = w.w;
    // wave-private LDS slab: same-wave DS ordering suffices, no barrier
    int iters = (m + 3) >> 2;
    for (int g = 0; g < iters; ++g) {
      int jb = g * 4;
      int se = svs[wv][jb + e4];
      float we = myp[wv][jb + e4][t];      // 0 for dead edge slots
      h4v fv = *(const h4v*)(feat2h + (size_t)se * 64 + t * 16 + fq * 4);
      l += we;
      acc[0] = fmaf(we, (float)fv[0], acc[0]);
      acc[1] = fmaf(we, (float)fv[1], acc[1]);
      acc[2] = fmaf(we, (float)fv[2], acc[2]);
      acc[3] = fmaf(we, (float)fv[3], acc[3]);
    }
  }
  // reduce over the 4 edge-slots (lane bits 4,5)
#pragma unroll
  for (int mask = 16; mask <= 32; mask <<= 1) {
#pragma unroll
    for (int k = 0; k < 4; ++k) acc[k] += __shfl_xor(acc[k], mask);
    l += __shfl_xor(l, mask);
  }
  if (e4 == 0) {
    float inv = (l > 0.f) ? (1.f / l) : 0.f;
    float4 r;
    r.x = acc[0] * inv + b2[fq * 4 + 0];
    r.y = acc[1] * inv + b2[fq * 4 + 1];
    r.z = acc[2] * inv + b2[fq * 4 + 2];
    r.w = acc[3] * inv + b2[fq * 4 + 3];
    *(float4*)&out[(size_t)(n * TT + t) * OUT_F + fq * 4] = r;
  }
}

// ---------------------------------------------------------------------------
extern "C" void kernel_launch(void* const* d_in, const int* in_sizes, int n_in,
                              void* d_out, int out_size, void* d_ws, size_t ws_size,
                              hipStream_t stream) {
  const float* x   = (const float*)d_in[0];
  const int*   src = (const int*)d_in[1];
  const int*   dst = (const int*)d_in[2];
  const float* W1  = (const float*)d_in[3];
  const float* al1 = (const float*)d_in[4];
  const float* ar1 = (const float*)d_in[5];
  const float* b1  = (const float*)d_in[6];
  const float* W2  = (const float*)d_in[7];
  const float* al2 = (const float*)d_in[8];
  const float* ar2 = (const float*)d_in[9];
  const float* b2  = (const float*)d_in[10];
  float* out = (float*)d_out;

  // Workspace layout (bytes, 256-aligned chunks), ~37 MB total
  char* w = (char*)d_ws;
  __half* feat1h = (__half*)w; w += (size_t)NT * C1 * 2;        // 20.48 MB
  __half* feat2h = (__half*)w; w += (size_t)NT * OUT_F * 2;     // 2.56 MB
  float*  el1    = (float*)w;  w += (size_t)NT * H1 * 4;        // 2.56 MB
  float*  er1    = (float*)w;  w += (size_t)NT * H1 * 4;
  float*  el2    = (float*)w;  w += (size_t)NT * 4;             // 0.32 MB
  float*  er2    = (float*)w;  w += (size_t)NT * 4;
  int* cnt     = (int*)w;      w += (size_t)NN * 4;             // 80 KB
  int* csr96   = (int*)w;      w += (size_t)NN * CAP * 4;       // 7.68 MB

  hipMemsetAsync(cnt, 0, NN * sizeof(int), stream);

  k_front<<<SCAT_BLOCKS + FEAT1_BLOCKS, 256, 0, stream>>>(
      x, W1, al1, ar1, (const int4*)src, (const int4*)dst, cnt, csr96,
      feat1h, el1, er1);
  k_agg1f<<<NN / 4, 256, 0, stream>>>(
      feat1h, el1, er1, cnt, csr96, b1, W2, al2, ar2, feat2h, el2, er2);
  k_agg2<<<NN / 4, 256, 0, stream>>>(feat2h, el2, er2, cnt, csr96, b2, out);
}

// Round 10
// 187.869 us; speedup vs baseline: 1.0861x; 1.0861x over previous
//
#include <hip/hip_runtime.h>
#include <hip/hip_fp16.h>
#include <math.h>

// Problem constants (from reference)
#define NN 20000          // nodes
#define TT 4              // time steps
#define EE 320000         // edges
#define NT (NN*TT)        // 80000 rows
#define H1 8              // heads layer 1
#define C1 128            // heads*f_out layer 1
#define IN_F 32
#define OUT_F 16
#define CAP 96            // bucket capacity; max degree Poisson(16) << 96
#define SCAT_BLOCKS 313   // ceil((EE/4)/256)
#define FEAT1_BLOCKS 1250 // NT/64

typedef _Float16 h8 __attribute__((ext_vector_type(8)));
typedef _Float16 h4v __attribute__((ext_vector_type(4)));
typedef float f32x4 __attribute__((ext_vector_type(4)));

__device__ __forceinline__ float lrelu_exp(float e) {
  e = (e >= 0.f) ? e : 0.2f * e;
  return __expf(e);
}

// ---------------------------------------------------------------------------
// K1 "front": blocks 0..312 = bucket-CSR scatter (start first: longer pole);
// blocks 313.. = feat1 MFMA GEMM with per-block LDS W1p build.
// ---------------------------------------------------------------------------
__global__ __launch_bounds__(256) void k_front(
    const float* __restrict__ x, const float* __restrict__ W1,
    const float* __restrict__ al1, const float* __restrict__ ar1,
    const int4* __restrict__ src4, const int4* __restrict__ dst4,
    int* __restrict__ cnt, int* __restrict__ csr96,
    __half* __restrict__ feat1h, float* __restrict__ el1,
    float* __restrict__ er1) {
  __shared__ h8 W1ps[9 * 64];            // 9.2 KB, feat1 branch only
  int b = blockIdx.x;
  int tid = threadIdx.x;
  if (b < SCAT_BLOCKS) {
    int e4 = b * 256 + tid;
    if (e4 < EE / 4) {
      int4 s = src4[e4];
      int4 d = dst4[e4];
      int p0 = atomicAdd(&cnt[d.x], 1); csr96[d.x * CAP + p0] = s.x;
      int p1 = atomicAdd(&cnt[d.y], 1); csr96[d.y * CAP + p1] = s.y;
      int p2 = atomicAdd(&cnt[d.z], 1); csr96[d.z * CAP + p2] = s.z;
      int p3 = atomicAdd(&cnt[d.w], 1); csr96[d.w * CAP + p3] = s.w;
    }
    return;
  }
  // ---- feat1 branch ----
  __half* W1p = (__half*)W1ps;
  for (int idx = tid; idx < 9 * 512; idx += 256) {
    int tile = idx >> 9;
    int rem = idx & 511;
    int lane = rem >> 3, j = rem & 7;
    int k = (lane >> 4) * 8 + j;
    int n = lane & 15;
    float v;
    if (tile < 8) {
      v = W1[k * C1 + tile * 16 + n];
    } else {
      int hh_ = n & 7;
      const float* a = (n < 8) ? al1 : ar1;
      float s = 0.f;
      for (int f = 0; f < 16; ++f) s += W1[k * C1 + hh_ * 16 + f] * a[hh_ * 16 + f];
      v = s;
    }
    W1p[idx] = __float2half(v);
  }
  __syncthreads();
  int wave = tid >> 6, lane = tid & 63;
  int m = lane & 15, quad = lane >> 4;
  int rowbase = (b - SCAT_BLOCKS) * 64 + wave * 16;
  int row = rowbase + m;
  const float4* xp = (const float4*)(x + row * IN_F + quad * 8);
  float4 a0 = xp[0], a1 = xp[1];
  h8 af;
  af[0] = (_Float16)a0.x; af[1] = (_Float16)a0.y;
  af[2] = (_Float16)a0.z; af[3] = (_Float16)a0.w;
  af[4] = (_Float16)a1.x; af[5] = (_Float16)a1.y;
  af[6] = (_Float16)a1.z; af[7] = (_Float16)a1.w;
#pragma unroll
  for (int ht = 0; ht < 8; ++ht) {
    h8 bf = W1ps[ht * 64 + lane];
    f32x4 c = {0.f, 0.f, 0.f, 0.f};
    c = __builtin_amdgcn_mfma_f32_16x16x32_f16(af, bf, c, 0, 0, 0);
#pragma unroll
    for (int r = 0; r < 4; ++r)
      feat1h[(size_t)(rowbase + quad * 4 + r) * C1 + ht * 16 + m] = __float2half(c[r]);
  }
  {
    h8 bf = W1ps[8 * 64 + lane];
    f32x4 c = {0.f, 0.f, 0.f, 0.f};
    c = __builtin_amdgcn_mfma_f32_16x16x32_f16(af, bf, c, 0, 0, 0);
#pragma unroll
    for (int r = 0; r < 4; ++r) {
      int orow = rowbase + quad * 4 + r;
      if (m < 8) el1[orow * H1 + m] = c[r];
      else       er1[orow * H1 + (m - 8)] = c[r];
    }
  }
}

// ---------------------------------------------------------------------------
// K2: layer-1 softmax-aggregate (exact R8 structure — do NOT graft cold code
// onto this loop; R9's fused epilogue doubled its runtime). One wave per
// node, all 4 t; 8-edge software pipeline: 8 readlane -> 8 el loads ->
// 8 feat-row loads (16 VMEM in flight) -> exp/shfl/fma consume.
// ---------------------------------------------------------------------------
__global__ __launch_bounds__(256) void k_agg1(
    const __half* __restrict__ feat1h,   // [n*4+t][128]
    const float* __restrict__ el1,       // [n][32] = [n][t][8]
    const float* __restrict__ er1,
    const int* __restrict__ cnt, const int* __restrict__ csr96,
    const float* __restrict__ b1, __half* __restrict__ hh) {
  int tid = threadIdx.x;
  int wv = tid >> 6, lane = tid & 63;
  int n = blockIdx.x * 4 + wv;
  int ci = lane & 15;
  int i32 = lane & 31;                       // (t,h) slot this lane computes
  int src_lane = ((lane >> 4) << 3) + (ci >> 1);  // t*8 + hh
  float er_i = er1[(size_t)n * 32 + i32];
  int deg = cnt[n];
  const int* eb = csr96 + (size_t)n * CAP;
  float acc[8];
#pragma unroll
  for (int k = 0; k < 8; ++k) acc[k] = 0.f;
  float l = 0.f;
  for (int chunk = 0; chunk < deg; chunk += 64) {
    int m = min(64, deg - chunk);
    int sv = (lane < m) ? eb[chunk + lane] : 0;
    int iters = (m + 7) >> 3;
    for (int g = 0; g < iters; ++g) {
      int j = g * 8;
      int s0 = __builtin_amdgcn_readlane(sv, j + 0);
      int s1 = __builtin_amdgcn_readlane(sv, j + 1);
      int s2 = __builtin_amdgcn_readlane(sv, j + 2);
      int s3 = __builtin_amdgcn_readlane(sv, j + 3);
      int s4 = __builtin_amdgcn_readlane(sv, j + 4);
      int s5 = __builtin_amdgcn_readlane(sv, j + 5);
      int s6 = __builtin_amdgcn_readlane(sv, j + 6);
      int s7 = __builtin_amdgcn_readlane(sv, j + 7);
      float ew0 = el1[(size_t)s0 * 32 + i32];
      float ew1 = el1[(size_t)s1 * 32 + i32];
      float ew2 = el1[(size_t)s2 * 32 + i32];
      float ew3 = el1[(size_t)s3 * 32 + i32];
      float ew4 = el1[(size_t)s4 * 32 + i32];
      float ew5 = el1[(size_t)s5 * 32 + i32];
      float ew6 = el1[(size_t)s6 * 32 + i32];
      float ew7 = el1[(size_t)s7 * 32 + i32];
      h8 f0 = *(const h8*)(feat1h + (size_t)s0 * 512 + lane * 8);
      h8 f1 = *(const h8*)(feat1h + (size_t)s1 * 512 + lane * 8);
      h8 f2 = *(const h8*)(feat1h + (size_t)s2 * 512 + lane * 8);
      h8 f3 = *(const h8*)(feat1h + (size_t)s3 * 512 + lane * 8);
      h8 f4 = *(const h8*)(feat1h + (size_t)s4 * 512 + lane * 8);
      h8 f5 = *(const h8*)(feat1h + (size_t)s5 * 512 + lane * 8);
      h8 f6 = *(const h8*)(feat1h + (size_t)s6 * 512 + lane * 8);
      h8 f7 = *(const h8*)(feat1h + (size_t)s7 * 512 + lane * 8);
#define CONSUME(K, EW, F)                                         \
      {                                                           \
        float w_ = lrelu_exp(EW + er_i);                          \
        w_ = (j + K < m) ? w_ : 0.f;                              \
        float wb_ = __shfl(w_, src_lane);                         \
        l += wb_;                                                 \
        _Pragma("unroll")                                         \
        for (int q = 0; q < 8; ++q)                               \
          acc[q] = fmaf(wb_, (float)F[q], acc[q]);                \
      }
      CONSUME(0, ew0, f0) CONSUME(1, ew1, f1)
      CONSUME(2, ew2, f2) CONSUME(3, ew3, f3)
      CONSUME(4, ew4, f4) CONSUME(5, ew5, f5)
      CONSUME(6, ew6, f6) CONSUME(7, ew7, f7)
#undef CONSUME
    }
  }
  float inv = (l > 0.f) ? (1.f / l) : 0.f;
  float4 bv0 = *(const float4*)&b1[ci * 8];
  float4 bv1 = *(const float4*)&b1[ci * 8 + 4];
  h8 r;
  r[0] = (_Float16)(acc[0] * inv + bv0.x);
  r[1] = (_Float16)(acc[1] * inv + bv0.y);
  r[2] = (_Float16)(acc[2] * inv + bv0.z);
  r[3] = (_Float16)(acc[3] * inv + bv0.w);
  r[4] = (_Float16)(acc[4] * inv + bv1.x);
  r[5] = (_Float16)(acc[5] * inv + bv1.y);
  r[6] = (_Float16)(acc[6] * inv + bv1.z);
  r[7] = (_Float16)(acc[7] * inv + bv1.w);
  *(h8*)(hh + (size_t)n * 512 + lane * 8) = r;
}

// ---------------------------------------------------------------------------
// K3: feat2 = h @ W2 via MFMA; el2/er2 fused as a second B-tile. W2p built
// in LDS per block (L2-resident reads, no global prep buffer needed).
// ---------------------------------------------------------------------------
__global__ __launch_bounds__(256) void k_feat2(
    const __half* __restrict__ hh, const float* __restrict__ W2,
    const float* __restrict__ al2, const float* __restrict__ ar2,
    __half* __restrict__ feat2h, float* __restrict__ el2, float* __restrict__ er2) {
  __shared__ h8 W2ps[8 * 64];            // 8 KB
  int tid = threadIdx.x;
  {
    __half* W2p = (__half*)W2ps;
    for (int idx = tid; idx < 8 * 512; idx += 256) {
      int tile = idx >> 9;
      int rem = idx & 511;
      int lane = rem >> 3, j = rem & 7;
      int ks = tile & 3;
      int k = ks * 32 + (lane >> 4) * 8 + j;
      int n = lane & 15;
      float v = 0.f;
      if (tile < 4) {
        v = W2[k * OUT_F + n];
      } else if (n == 0) {
        float s = 0.f;
        for (int f = 0; f < 16; ++f) s += W2[k * OUT_F + f] * al2[f];
        v = s;
      } else if (n == 1) {
        float s = 0.f;
        for (int f = 0; f < 16; ++f) s += W2[k * OUT_F + f] * ar2[f];
        v = s;
      }
      W2p[idx] = __float2half(v);
    }
  }
  __syncthreads();
  int wave = tid >> 6, lane = tid & 63;
  int m = lane & 15, quad = lane >> 4;
  int rowbase = blockIdx.x * 64 + wave * 16;
  const h8* hp = (const h8*)hh;          // [row][16] h8 chunks
  f32x4 cF = {0.f, 0.f, 0.f, 0.f};
  f32x4 cE = {0.f, 0.f, 0.f, 0.f};
#pragma unroll
  for (int ks = 0; ks < 4; ++ks) {
    h8 af = hp[(size_t)(rowbase + m) * 16 + ks * 4 + quad];
    cF = __builtin_amdgcn_mfma_f32_16x16x32_f16(af, W2ps[ks * 64 + lane], cF, 0, 0, 0);
    cE = __builtin_amdgcn_mfma_f32_16x16x32_f16(af, W2ps[(4 + ks) * 64 + lane], cE, 0, 0, 0);
  }
#pragma unroll
  for (int r = 0; r < 4; ++r) {
    int orow = rowbase + quad * 4 + r;
    feat2h[(size_t)orow * OUT_F + m] = __float2half(cF[r]);
    if (m == 0) el2[orow] = cE[r];
    if (m == 1) er2[orow] = cE[r];
  }
}

// ---------------------------------------------------------------------------
// K4: layer-2 aggregate. One wave per node; 4 edges per iteration
// (16 lanes/edge, one 8B h4 load each). Weights in wave-private LDS with
// stride-5 padding; butterfly-reduce over the 4 edge-slots at the end.
// ---------------------------------------------------------------------------
__global__ __launch_bounds__(256) void k_agg2(
    const __half* __restrict__ feat2h,     // [n*4+t][16]
    const float* __restrict__ el2, const float* __restrict__ er2,  // [n*4+t]
    const int* __restrict__ cnt, const int* __restrict__ csr96,
    const float* __restrict__ b2, float* __restrict__ out) {
  __shared__ float myp[4][64][5];          // stride-5 pad: conflict-free
  __shared__ int   svs[4][64];
  int tid = threadIdx.x;
  int wv = tid >> 6, lane = tid & 63;
  int n = blockIdx.x * 4 + wv;
  int e4 = lane >> 4, sub = lane & 15;
  int t = sub >> 2, fq = sub & 3;          // 4 channels fq*4..fq*4+3
  int deg = cnt[n];
  const int* eb = csr96 + (size_t)n * CAP;
  float4 ern = *(const float4*)&er2[n * TT];
  float acc[4] = {0.f, 0.f, 0.f, 0.f};
  float l = 0.f;
  for (int chunk = 0; chunk < deg; chunk += 64) {
    int m = min(64, deg - chunk);
    float4 w = {0.f, 0.f, 0.f, 0.f};
    int s = 0;
    if (lane < m) {
      s = eb[chunk + lane];
      float4 e = *(const float4*)&el2[s * TT];
      w.x = lrelu_exp(e.x + ern.x);
      w.y = lrelu_exp(e.y + ern.y);
      w.z = lrelu_exp(e.z + ern.z);
      w.w = lrelu_exp(e.w + ern.w);
    }
    svs[wv][lane] = s;
    myp[wv][lane][0] = w.x;
    myp[wv][lane][1] = w.y;
    myp[wv][lane][2] = w.z;
    myp[wv][lane][3] = w.w;
    // wave-private LDS slab: same-wave DS ordering suffices, no barrier
    int iters = (m + 3) >> 2;
    for (int g = 0; g < iters; ++g) {
      int jb = g * 4;
      int se = svs[wv][jb + e4];
      float we = myp[wv][jb + e4][t];      // 0 for dead edge slots
      h4v fv = *(const h4v*)(feat2h + (size_t)se * 64 + t * 16 + fq * 4);
      l += we;
      acc[0] = fmaf(we, (float)fv[0], acc[0]);
      acc[1] = fmaf(we, (float)fv[1], acc[1]);
      acc[2] = fmaf(we, (float)fv[2], acc[2]);
      acc[3] = fmaf(we, (float)fv[3], acc[3]);
    }
  }
  // reduce over the 4 edge-slots (lane bits 4,5)
#pragma unroll
  for (int mask = 16; mask <= 32; mask <<= 1) {
#pragma unroll
    for (int k = 0; k < 4; ++k) acc[k] += __shfl_xor(acc[k], mask);
    l += __shfl_xor(l, mask);
  }
  if (e4 == 0) {
    float inv = (l > 0.f) ? (1.f / l) : 0.f;
    float4 r;
    r.x = acc[0] * inv + b2[fq * 4 + 0];
    r.y = acc[1] * inv + b2[fq * 4 + 1];
    r.z = acc[2] * inv + b2[fq * 4 + 2];
    r.w = acc[3] * inv + b2[fq * 4 + 3];
    *(float4*)&out[(size_t)(n * TT + t) * OUT_F + fq * 4] = r;
  }
}

// ---------------------------------------------------------------------------
extern "C" void kernel_launch(void* const* d_in, const int* in_sizes, int n_in,
                              void* d_out, int out_size, void* d_ws, size_t ws_size,
                              hipStream_t stream) {
  const float* x   = (const float*)d_in[0];
  const int*   src = (const int*)d_in[1];
  const int*   dst = (const int*)d_in[2];
  const float* W1  = (const float*)d_in[3];
  const float* al1 = (const float*)d_in[4];
  const float* ar1 = (const float*)d_in[5];
  const float* b1  = (const float*)d_in[6];
  const float* W2  = (const float*)d_in[7];
  const float* al2 = (const float*)d_in[8];
  const float* ar2 = (const float*)d_in[9];
  const float* b2  = (const float*)d_in[10];
  float* out = (float*)d_out;

  // Workspace layout (bytes, 256-aligned chunks), ~57 MB total
  char* w = (char*)d_ws;
  __half* feat1h = (__half*)w; w += (size_t)NT * C1 * 2;        // 20.48 MB
  __half* hh     = (__half*)w; w += (size_t)NT * C1 * 2;        // 20.48 MB
  __half* feat2h = (__half*)w; w += (size_t)NT * OUT_F * 2;     // 2.56 MB
  float*  el1    = (float*)w;  w += (size_t)NT * H1 * 4;        // 2.56 MB
  float*  er1    = (float*)w;  w += (size_t)NT * H1 * 4;
  float*  el2    = (float*)w;  w += (size_t)NT * 4;             // 0.32 MB
  float*  er2    = (float*)w;  w += (size_t)NT * 4;
  int* cnt     = (int*)w;      w += (size_t)NN * 4;             // 80 KB
  int* csr96   = (int*)w;      w += (size_t)NN * CAP * 4;       // 7.68 MB

  hipMemsetAsync(cnt, 0, NN * sizeof(int), stream);

  k_front<<<SCAT_BLOCKS + FEAT1_BLOCKS, 256, 0, stream>>>(
      x, W1, al1, ar1, (const int4*)src, (const int4*)dst, cnt, csr96,
      feat1h, el1, er1);
  k_agg1<<<NN / 4, 256, 0, stream>>>(feat1h, el1, er1, cnt, csr96, b1, hh);
  k_feat2<<<NT / 64, 256, 0, stream>>>(hh, W2, al2, ar2, feat2h, el2, er2);
  k_agg2<<<NN / 4, 256, 0, stream>>>(feat2h, el2, er2, cnt, csr96, b2, out);
}

// Round 11
// 178.002 us; speedup vs baseline: 1.1463x; 1.0554x over previous
//
#include <hip/hip_runtime.h>
#include <hip/hip_fp16.h>
#include <math.h>

// Problem constants (from reference)
#define NN 20000          // nodes
#define TT 4              // time steps
#define EE 320000         // edges
#define NT (NN*TT)        // 80000 rows
#define H1 8              // heads layer 1
#define C1 128            // heads*f_out layer 1
#define IN_F 32
#define OUT_F 16
#define CAP 96            // bucket capacity; max degree Poisson(16) << 96
#define SCAT_BLOCKS 313   // ceil((EE/4)/256)
#define XCAST_BLOCKS 1250 // NT/64

typedef _Float16 h8 __attribute__((ext_vector_type(8)));
typedef float f32x4 __attribute__((ext_vector_type(4)));

__device__ __forceinline__ float lrelu_exp(float e) {
  e = (e >= 0.f) ? e : 0.2f * e;
  return __expf(e);
}

// ---------------------------------------------------------------------------
// K1 "front": blocks 0..312 = bucket-CSR scatter; block 313 = global weight
// prep (W1hp per-head B-frags + W2pp); blocks 314.. = x cast to fp16 +
// el1/er1 via one ELER MFMA (ELER tile built in LDS: it's 1 tile, cheap).
// NOTE: k_mid/k_feat2 consume W1hp/W2pp in LATER launches — no race.
// ---------------------------------------------------------------------------
__global__ __launch_bounds__(256) void k_front(
    const float* __restrict__ x, const float* __restrict__ W1,
    const float* __restrict__ al1, const float* __restrict__ ar1,
    const float* __restrict__ W2, const float* __restrict__ al2,
    const float* __restrict__ ar2,
    const int4* __restrict__ src4, const int4* __restrict__ dst4,
    int* __restrict__ cnt, int* __restrict__ csr96,
    __half* __restrict__ xh, float* __restrict__ el1, float* __restrict__ er1,
    __half* __restrict__ W1hp, __half* __restrict__ W2pp) {
  __shared__ h8 ELERs[64];               // 1 KB, xcast branch only
  int b = blockIdx.x;
  int tid = threadIdx.x;
  if (b < SCAT_BLOCKS) {
    int e4 = b * 256 + tid;
    if (e4 < EE / 4) {
      int4 s = src4[e4];
      int4 d = dst4[e4];
      int p0 = atomicAdd(&cnt[d.x], 1); csr96[d.x * CAP + p0] = s.x;
      int p1 = atomicAdd(&cnt[d.y], 1); csr96[d.y * CAP + p1] = s.y;
      int p2 = atomicAdd(&cnt[d.z], 1); csr96[d.z * CAP + p2] = s.z;
      int p3 = atomicAdd(&cnt[d.w], 1); csr96[d.w * CAP + p3] = s.w;
    }
    return;
  }
  if (b == SCAT_BLOCKS) {
    // W1hp: 8 per-head B-frag tiles, B[k][n] with n=lane&15, k=(lane>>4)*8+j
    for (int idx = tid; idx < 8 * 512; idx += 256) {
      int tile = idx >> 9;
      int rem = idx & 511;
      int lane = rem >> 3, j = rem & 7;
      int k = (lane >> 4) * 8 + j;
      int n = lane & 15;
      W1hp[idx] = __float2half(W1[k * C1 + tile * 16 + n]);
    }
    // W2pp: 4 feat k-step tiles + 4 [Wl2|Wr2|0] k-step tiles
    for (int idx = tid; idx < 8 * 512; idx += 256) {
      int tile = idx >> 9;
      int rem = idx & 511;
      int lane = rem >> 3, j = rem & 7;
      int ks = tile & 3;
      int k = ks * 32 + (lane >> 4) * 8 + j;
      int n = lane & 15;
      float v = 0.f;
      if (tile < 4) {
        v = W2[k * OUT_F + n];
      } else if (n == 0) {
        float s = 0.f;
        for (int f = 0; f < 16; ++f) s += W2[k * OUT_F + f] * al2[f];
        v = s;
      } else if (n == 1) {
        float s = 0.f;
        for (int f = 0; f < 16; ++f) s += W2[k * OUT_F + f] * ar2[f];
        v = s;
      }
      W2pp[idx] = __float2half(v);
    }
    return;
  }
  // ---- xcast + el/er branch ----
  {
    __half* E = (__half*)ELERs;
    for (int idx = tid; idx < 512; idx += 256) {
      int lane = idx >> 3, j = idx & 7;
      int k = (lane >> 4) * 8 + j;
      int n = lane & 15;
      int hh_ = n & 7;
      const float* a = (n < 8) ? al1 : ar1;
      float s = 0.f;
      for (int f = 0; f < 16; ++f) s += W1[k * C1 + hh_ * 16 + f] * a[hh_ * 16 + f];
      E[idx] = __float2half(s);
    }
  }
  __syncthreads();
  int wave = tid >> 6, lane = tid & 63;
  int m = lane & 15, quad = lane >> 4;
  int rowbase = (b - SCAT_BLOCKS - 1) * 64 + wave * 16;
  int row = rowbase + m;
  const float4* xp = (const float4*)(x + row * IN_F + quad * 8);
  float4 a0 = xp[0], a1 = xp[1];
  h8 af;
  af[0] = (_Float16)a0.x; af[1] = (_Float16)a0.y;
  af[2] = (_Float16)a0.z; af[3] = (_Float16)a0.w;
  af[4] = (_Float16)a1.x; af[5] = (_Float16)a1.y;
  af[6] = (_Float16)a1.z; af[7] = (_Float16)a1.w;
  *(h8*)(xh + (size_t)row * IN_F + quad * 8) = af;   // fp16 x copy
  {
    h8 bf = ELERs[lane];
    f32x4 c = {0.f, 0.f, 0.f, 0.f};
    c = __builtin_amdgcn_mfma_f32_16x16x32_f16(af, bf, c, 0, 0, 0);
#pragma unroll
    for (int r = 0; r < 4; ++r) {
      int orow = rowbase + quad * 4 + r;
      if (m < 8) el1[orow * H1 + m] = c[r];
      else       er1[orow * H1 + (m - 8)] = c[r];
    }
  }
}

// ---------------------------------------------------------------------------
// K2: layer-1 x-form aggregate. GEMM/sum commuted: aggx[n,t,h,:] =
// sum_e alpha * xh[s,t,:] / l[t,h]. One wave per node; lane owns slot
// (t,h) = lane>>1 and 16 channels (half = lane&1). alpha computed LOCALLY
// per lane (el load is 2-lane-duplicated = same cache line) — no shfl, no
// LDS in the hot loop. Per edge: 1 el load + 2 h8 x loads + 16 fma.
// ---------------------------------------------------------------------------
__global__ __launch_bounds__(256) void k_agg1x(
    const __half* __restrict__ xh,       // [nt][32]
    const float* __restrict__ el1,       // [n][32] = [n][t][8]
    const float* __restrict__ er1,
    const int* __restrict__ cnt, const int* __restrict__ csr96,
    __half* __restrict__ aggx) {         // [nt][8h][32]
  int tid = threadIdx.x;
  int wv = tid >> 6, lane = tid & 63;
  int n = blockIdx.x * 4 + wv;
  int slot = lane >> 1;                  // (t,h): t=slot>>3, h=slot&7
  int t = lane >> 4;                     // == slot>>3
  int half = lane & 1;
  float er_i = er1[(size_t)n * 32 + slot];
  int deg = cnt[n];
  const int* eb = csr96 + (size_t)n * CAP;
  float acc[16];
#pragma unroll
  for (int k = 0; k < 16; ++k) acc[k] = 0.f;
  float l = 0.f;
  for (int chunk = 0; chunk < deg; chunk += 64) {
    int m = min(64, deg - chunk);
    int sv = (lane < m) ? eb[chunk + lane] : 0;
    int iters = (m + 3) >> 2;
    for (int g = 0; g < iters; ++g) {
      int j = g * 4;
      int s0 = __builtin_amdgcn_readlane(sv, j + 0);
      int s1 = __builtin_amdgcn_readlane(sv, j + 1);
      int s2 = __builtin_amdgcn_readlane(sv, j + 2);
      int s3 = __builtin_amdgcn_readlane(sv, j + 3);
      float ew0 = el1[(size_t)s0 * 32 + slot];
      float ew1 = el1[(size_t)s1 * 32 + slot];
      float ew2 = el1[(size_t)s2 * 32 + slot];
      float ew3 = el1[(size_t)s3 * 32 + slot];
      const __half* x0 = xh + (size_t)(s0 * 4 + t) * 32 + half * 16;
      const __half* x1 = xh + (size_t)(s1 * 4 + t) * 32 + half * 16;
      const __half* x2 = xh + (size_t)(s2 * 4 + t) * 32 + half * 16;
      const __half* x3 = xh + (size_t)(s3 * 4 + t) * 32 + half * 16;
      h8 a0 = *(const h8*)x0, b0 = *(const h8*)(x0 + 8);
      h8 a1 = *(const h8*)x1, b1_ = *(const h8*)(x1 + 8);
      h8 a2 = *(const h8*)x2, b2_ = *(const h8*)(x2 + 8);
      h8 a3 = *(const h8*)x3, b3_ = *(const h8*)(x3 + 8);
#define CONSUME(K, EW, XA, XB)                                    \
      {                                                           \
        float w_ = lrelu_exp(EW + er_i);                          \
        w_ = (j + K < m) ? w_ : 0.f;                              \
        l += w_;                                                  \
        _Pragma("unroll")                                         \
        for (int q = 0; q < 8; ++q) {                             \
          acc[q]     = fmaf(w_, (float)XA[q], acc[q]);            \
          acc[8 + q] = fmaf(w_, (float)XB[q], acc[8 + q]);        \
        }                                                         \
      }
      CONSUME(0, ew0, a0, b0) CONSUME(1, ew1, a1, b1_)
      CONSUME(2, ew2, a2, b2_) CONSUME(3, ew3, a3, b3_)
#undef CONSUME
    }
  }
  float inv = (l > 0.f) ? (1.f / l) : 0.f;
  h8 r0, r1;
#pragma unroll
  for (int q = 0; q < 8; ++q) {
    r0[q] = (_Float16)(acc[q] * inv);
    r1[q] = (_Float16)(acc[8 + q] * inv);
  }
  int hh_ = slot & 7;
  __half* op = aggx + (size_t)(n * 4 + t) * 256 + hh_ * 32 + half * 16;
  *(h8*)op = r0;
  *(h8*)(op + 8) = r1;
}

// ---------------------------------------------------------------------------
// K3: h = per-head GEMM of aggx vs W1 (+b1), fp16 out. 8 MFMAs per 16-row
// tile, one per head; W1hp prepped globally by k_front block 313.
// ---------------------------------------------------------------------------
__global__ __launch_bounds__(256) void k_mid(
    const __half* __restrict__ aggx,     // [nt][8][32]
    const __half* __restrict__ W1hp, const float* __restrict__ b1,
    __half* __restrict__ hbuf) {         // [nt][128]
  int tid = threadIdx.x;
  int wave = tid >> 6, lane = tid & 63;
  int m = lane & 15, quad = lane >> 4;
  int rowbase = blockIdx.x * 64 + wave * 16;
  const h8* bp = (const h8*)W1hp;
#pragma unroll
  for (int hh_ = 0; hh_ < 8; ++hh_) {
    h8 af = *(const h8*)(aggx + (size_t)(rowbase + m) * 256 + hh_ * 32 + quad * 8);
    f32x4 c = {0.f, 0.f, 0.f, 0.f};
    c = __builtin_amdgcn_mfma_f32_16x16x32_f16(af, bp[hh_ * 64 + lane], c, 0, 0, 0);
    float bv = b1[hh_ * 16 + m];
#pragma unroll
    for (int r = 0; r < 4; ++r)
      hbuf[(size_t)(rowbase + quad * 4 + r) * C1 + hh_ * 16 + m] =
          __float2half(c[r] + bv);
  }
}

// ---------------------------------------------------------------------------
// K4: feat2 = h @ W2 via MFMA; el2/er2 fused as second B-tile (W2pp global).
// ---------------------------------------------------------------------------
__global__ __launch_bounds__(256) void k_feat2(
    const __half* __restrict__ hbuf, const __half* __restrict__ W2pp,
    __half* __restrict__ feat2h, float* __restrict__ el2, float* __restrict__ er2) {
  int tid = threadIdx.x;
  int wave = tid >> 6, lane = tid & 63;
  int m = lane & 15, quad = lane >> 4;
  int rowbase = blockIdx.x * 64 + wave * 16;
  const h8* hp = (const h8*)hbuf;        // [row][16] h8 chunks
  const h8* bp = (const h8*)W2pp;
  f32x4 cF = {0.f, 0.f, 0.f, 0.f};
  f32x4 cE = {0.f, 0.f, 0.f, 0.f};
#pragma unroll
  for (int ks = 0; ks < 4; ++ks) {
    h8 af = hp[(size_t)(rowbase + m) * 16 + ks * 4 + quad];
    cF = __builtin_amdgcn_mfma_f32_16x16x32_f16(af, bp[ks * 64 + lane], cF, 0, 0, 0);
    cE = __builtin_amdgcn_mfma_f32_16x16x32_f16(af, bp[(4 + ks) * 64 + lane], cE, 0, 0, 0);
  }
#pragma unroll
  for (int r = 0; r < 4; ++r) {
    int orow = rowbase + quad * 4 + r;
    feat2h[(size_t)orow * OUT_F + m] = __float2half(cF[r]);
    if (m == 0) el2[orow] = cE[r];
    if (m == 1) er2[orow] = cE[r];
  }
}

// ---------------------------------------------------------------------------
// K5: layer-2 aggregate, no-routing form. One wave per node; lane owns
// (t = lane>>4, f = lane&15); alpha computed locally (el2 load is
// 16-lane-duplicated broadcast); 1 fma per edge per lane. 8-edge batches.
// ---------------------------------------------------------------------------
__global__ __launch_bounds__(256) void k_agg2x(
    const __half* __restrict__ feat2h,   // [nt][16]
    const float* __restrict__ el2, const float* __restrict__ er2,  // [nt]
    const int* __restrict__ cnt, const int* __restrict__ csr96,
    const float* __restrict__ b2, float* __restrict__ out) {
  int tid = threadIdx.x;
  int wv = tid >> 6, lane = tid & 63;
  int n = blockIdx.x * 4 + wv;
  int t = lane >> 4, f = lane & 15;
  float ern = er2[n * 4 + t];
  int deg = cnt[n];
  const int* eb = csr96 + (size_t)n * CAP;
  float acc = 0.f, l = 0.f;
  for (int chunk = 0; chunk < deg; chunk += 64) {
    int m = min(64, deg - chunk);
    int sv = (lane < m) ? eb[chunk + lane] : 0;
    int iters = (m + 7) >> 3;
    for (int g = 0; g < iters; ++g) {
      int j = g * 8;
      int s0 = __builtin_amdgcn_readlane(sv, j + 0);
      int s1 = __builtin_amdgcn_readlane(sv, j + 1);
      int s2 = __builtin_amdgcn_readlane(sv, j + 2);
      int s3 = __builtin_amdgcn_readlane(sv, j + 3);
      int s4 = __builtin_amdgcn_readlane(sv, j + 4);
      int s5 = __builtin_amdgcn_readlane(sv, j + 5);
      int s6 = __builtin_amdgcn_readlane(sv, j + 6);
      int s7 = __builtin_amdgcn_readlane(sv, j + 7);
      float e0 = el2[s0 * 4 + t];
      float e1 = el2[s1 * 4 + t];
      float e2 = el2[s2 * 4 + t];
      float e3 = el2[s3 * 4 + t];
      float e4 = el2[s4 * 4 + t];
      float e5 = el2[s5 * 4 + t];
      float e6 = el2[s6 * 4 + t];
      float e7 = el2[s7 * 4 + t];
      __half f0 = feat2h[(size_t)(s0 * 4 + t) * OUT_F + f];
      __half f1 = feat2h[(size_t)(s1 * 4 + t) * OUT_F + f];
      __half f2 = feat2h[(size_t)(s2 * 4 + t) * OUT_F + f];
      __half f3 = feat2h[(size_t)(s3 * 4 + t) * OUT_F + f];
      __half f4 = feat2h[(size_t)(s4 * 4 + t) * OUT_F + f];
      __half f5 = feat2h[(size_t)(s5 * 4 + t) * OUT_F + f];
      __half f6 = feat2h[(size_t)(s6 * 4 + t) * OUT_F + f];
      __half f7 = feat2h[(size_t)(s7 * 4 + t) * OUT_F + f];
#define CONSUME(K, EW, FV)                                        \
      {                                                           \
        float w_ = lrelu_exp(EW + ern);                           \
        w_ = (j + K < m) ? w_ : 0.f;                              \
        l += w_;                                                  \
        acc = fmaf(w_, __half2float(FV), acc);                    \
      }
      CONSUME(0, e0, f0) CONSUME(1, e1, f1)
      CONSUME(2, e2, f2) CONSUME(3, e3, f3)
      CONSUME(4, e4, f4) CONSUME(5, e5, f5)
      CONSUME(6, e6, f6) CONSUME(7, e7, f7)
#undef CONSUME
    }
  }
  float inv = (l > 0.f) ? (1.f / l) : 0.f;
  out[(size_t)(n * 4 + t) * OUT_F + f] = acc * inv + b2[f];
}

// ---------------------------------------------------------------------------
extern "C" void kernel_launch(void* const* d_in, const int* in_sizes, int n_in,
                              void* d_out, int out_size, void* d_ws, size_t ws_size,
                              hipStream_t stream) {
  const float* x   = (const float*)d_in[0];
  const int*   src = (const int*)d_in[1];
  const int*   dst = (const int*)d_in[2];
  const float* W1  = (const float*)d_in[3];
  const float* al1 = (const float*)d_in[4];
  const float* ar1 = (const float*)d_in[5];
  const float* b1  = (const float*)d_in[6];
  const float* W2  = (const float*)d_in[7];
  const float* al2 = (const float*)d_in[8];
  const float* ar2 = (const float*)d_in[9];
  const float* b2  = (const float*)d_in[10];
  float* out = (float*)d_out;

  // Workspace layout (bytes, 256-aligned chunks), ~84 MB total
  char* w = (char*)d_ws;
  __half* xh     = (__half*)w; w += (size_t)NT * IN_F * 2;      // 5.12 MB
  __half* aggx   = (__half*)w; w += (size_t)NT * 256 * 2;       // 40.96 MB
  __half* hbuf   = (__half*)w; w += (size_t)NT * C1 * 2;        // 20.48 MB
  __half* feat2h = (__half*)w; w += (size_t)NT * OUT_F * 2;     // 2.56 MB
  float*  el1    = (float*)w;  w += (size_t)NT * H1 * 4;        // 2.56 MB
  float*  er1    = (float*)w;  w += (size_t)NT * H1 * 4;
  float*  el2    = (float*)w;  w += (size_t)NT * 4;             // 0.32 MB
  float*  er2    = (float*)w;  w += (size_t)NT * 4;
  __half* W1hp   = (__half*)w; w += (size_t)8 * 512 * 2;
  __half* W2pp   = (__half*)w; w += (size_t)8 * 512 * 2;
  int* cnt     = (int*)w;      w += (size_t)NN * 4;             // 80 KB
  int* csr96   = (int*)w;      w += (size_t)NN * CAP * 4;       // 7.68 MB

  hipMemsetAsync(cnt, 0, NN * sizeof(int), stream);

  k_front<<<SCAT_BLOCKS + 1 + XCAST_BLOCKS, 256, 0, stream>>>(
      x, W1, al1, ar1, W2, al2, ar2, (const int4*)src, (const int4*)dst,
      cnt, csr96, xh, el1, er1, W1hp, W2pp);
  k_agg1x<<<NN / 4, 256, 0, stream>>>(xh, el1, er1, cnt, csr96, aggx);
  k_mid<<<NT / 64, 256, 0, stream>>>(aggx, W1hp, b1, hbuf);
  k_feat2<<<NT / 64, 256, 0, stream>>>(hbuf, W2pp, feat2h, el2, er2);
  k_agg2x<<<NN / 4, 256, 0, stream>>>(feat2h, el2, er2, cnt, csr96, b2, out);
}

// Round 12
// 175.121 us; speedup vs baseline: 1.1652x; 1.0164x over previous
//
#include <hip/hip_runtime.h>
#include <hip/hip_fp16.h>
#include <math.h>

// Problem constants (from reference)
#define NN 20000          // nodes
#define TT 4              // time steps
#define EE 320000         // edges
#define NT (NN*TT)        // 80000 rows
#define H1 8              // heads layer 1
#define C1 128            // heads*f_out layer 1
#define IN_F 32
#define OUT_F 16
#define CAP 96            // bucket capacity; max degree Poisson(16) << 96
#define SCAT_BLOCKS 313   // ceil((EE/4)/256)
#define XCAST_BLOCKS 1250 // NT/64

typedef _Float16 h8 __attribute__((ext_vector_type(8)));
typedef float f32x4 __attribute__((ext_vector_type(4)));

__device__ __forceinline__ float lrelu_exp(float e) {
  e = (e >= 0.f) ? e : 0.2f * e;
  return __expf(e);
}

// ---------------------------------------------------------------------------
// K1 "front": blocks 0..312 = bucket-CSR scatter; block 313 = global weight
// prep (W1hp per-head B-frags + W2pp); blocks 314.. = x cast to fp16 +
// el1/er1 via one ELER MFMA (ELER tile built in LDS: 1 tile, cheap).
// ---------------------------------------------------------------------------
__global__ __launch_bounds__(256) void k_front(
    const float* __restrict__ x, const float* __restrict__ W1,
    const float* __restrict__ al1, const float* __restrict__ ar1,
    const float* __restrict__ W2, const float* __restrict__ al2,
    const float* __restrict__ ar2,
    const int4* __restrict__ src4, const int4* __restrict__ dst4,
    int* __restrict__ cnt, int* __restrict__ csr96,
    __half* __restrict__ xh, float* __restrict__ el1, float* __restrict__ er1,
    __half* __restrict__ W1hp, __half* __restrict__ W2pp) {
  __shared__ h8 ELERs[64];               // 1 KB, xcast branch only
  int b = blockIdx.x;
  int tid = threadIdx.x;
  if (b < SCAT_BLOCKS) {
    int e4 = b * 256 + tid;
    if (e4 < EE / 4) {
      int4 s = src4[e4];
      int4 d = dst4[e4];
      int p0 = atomicAdd(&cnt[d.x], 1); csr96[d.x * CAP + p0] = s.x;
      int p1 = atomicAdd(&cnt[d.y], 1); csr96[d.y * CAP + p1] = s.y;
      int p2 = atomicAdd(&cnt[d.z], 1); csr96[d.z * CAP + p2] = s.z;
      int p3 = atomicAdd(&cnt[d.w], 1); csr96[d.w * CAP + p3] = s.w;
    }
    return;
  }
  if (b == SCAT_BLOCKS) {
    // W1hp: 8 per-head B-frag tiles, B[k][n] with n=lane&15, k=(lane>>4)*8+j
    for (int idx = tid; idx < 8 * 512; idx += 256) {
      int tile = idx >> 9;
      int rem = idx & 511;
      int lane = rem >> 3, j = rem & 7;
      int k = (lane >> 4) * 8 + j;
      int n = lane & 15;
      W1hp[idx] = __float2half(W1[k * C1 + tile * 16 + n]);
    }
    // W2pp: 4 feat k-step tiles + 4 [Wl2|Wr2|0] k-step tiles
    for (int idx = tid; idx < 8 * 512; idx += 256) {
      int tile = idx >> 9;
      int rem = idx & 511;
      int lane = rem >> 3, j = rem & 7;
      int ks = tile & 3;
      int k = ks * 32 + (lane >> 4) * 8 + j;
      int n = lane & 15;
      float v = 0.f;
      if (tile < 4) {
        v = W2[k * OUT_F + n];
      } else if (n == 0) {
        float s = 0.f;
        for (int f = 0; f < 16; ++f) s += W2[k * OUT_F + f] * al2[f];
        v = s;
      } else if (n == 1) {
        float s = 0.f;
        for (int f = 0; f < 16; ++f) s += W2[k * OUT_F + f] * ar2[f];
        v = s;
      }
      W2pp[idx] = __float2half(v);
    }
    return;
  }
  // ---- xcast + el/er branch ----
  {
    __half* E = (__half*)ELERs;
    for (int idx = tid; idx < 512; idx += 256) {
      int lane = idx >> 3, j = idx & 7;
      int k = (lane >> 4) * 8 + j;
      int n = lane & 15;
      int hh_ = n & 7;
      const float* a = (n < 8) ? al1 : ar1;
      float s = 0.f;
      for (int f = 0; f < 16; ++f) s += W1[k * C1 + hh_ * 16 + f] * a[hh_ * 16 + f];
      E[idx] = __float2half(s);
    }
  }
  __syncthreads();
  int wave = tid >> 6, lane = tid & 63;
  int m = lane & 15, quad = lane >> 4;
  int rowbase = (b - SCAT_BLOCKS - 1) * 64 + wave * 16;
  int row = rowbase + m;
  const float4* xp = (const float4*)(x + row * IN_F + quad * 8);
  float4 a0 = xp[0], a1 = xp[1];
  h8 af;
  af[0] = (_Float16)a0.x; af[1] = (_Float16)a0.y;
  af[2] = (_Float16)a0.z; af[3] = (_Float16)a0.w;
  af[4] = (_Float16)a1.x; af[5] = (_Float16)a1.y;
  af[6] = (_Float16)a1.z; af[7] = (_Float16)a1.w;
  *(h8*)(xh + (size_t)row * IN_F + quad * 8) = af;   // fp16 x copy
  {
    h8 bf = ELERs[lane];
    f32x4 c = {0.f, 0.f, 0.f, 0.f};
    c = __builtin_amdgcn_mfma_f32_16x16x32_f16(af, bf, c, 0, 0, 0);
#pragma unroll
    for (int r = 0; r < 4; ++r) {
      int orow = rowbase + quad * 4 + r;
      if (m < 8) el1[orow * H1 + m] = c[r];
      else       er1[orow * H1 + (m - 8)] = c[r];
    }
  }
}

// ---------------------------------------------------------------------------
// K2: layer-1 x-form aggregate (GEMM/sum commuted). One wave per node; lane
// owns slot (t,h)=lane>>1 and 16 channels (hf=lane&1). alpha computed
// LOCALLY per lane — no shfl/LDS in hot loop. 8-edge groups: 8 el loads +
// 16 x-row h8 loads (24 VMEM in flight); deg~16 -> exactly 2 groups.
// ---------------------------------------------------------------------------
__global__ __launch_bounds__(256) void k_agg1x(
    const __half* __restrict__ xh,       // [nt][32]
    const float* __restrict__ el1,       // [n][32] = [n][t][8]
    const float* __restrict__ er1,
    const int* __restrict__ cnt, const int* __restrict__ csr96,
    __half* __restrict__ aggx) {         // [nt][8h][32]
  int tid = threadIdx.x;
  int wv = tid >> 6, lane = tid & 63;
  int n = blockIdx.x * 4 + wv;
  int slot = lane >> 1;                  // (t,h): t=slot>>3, h=slot&7
  int t = lane >> 4;                     // == slot>>3
  int hf = lane & 1;
  float er_i = er1[(size_t)n * 32 + slot];
  int deg = cnt[n];
  const int* eb = csr96 + (size_t)n * CAP;
  float acc[16];
#pragma unroll
  for (int k = 0; k < 16; ++k) acc[k] = 0.f;
  float l = 0.f;
  for (int chunk = 0; chunk < deg; chunk += 64) {
    int m = min(64, deg - chunk);
    int sv = (lane < m) ? eb[chunk + lane] : 0;
    int iters = (m + 7) >> 3;
    for (int g = 0; g < iters; ++g) {
      int j = g * 8;
      int s0 = __builtin_amdgcn_readlane(sv, j + 0);
      int s1 = __builtin_amdgcn_readlane(sv, j + 1);
      int s2 = __builtin_amdgcn_readlane(sv, j + 2);
      int s3 = __builtin_amdgcn_readlane(sv, j + 3);
      int s4 = __builtin_amdgcn_readlane(sv, j + 4);
      int s5 = __builtin_amdgcn_readlane(sv, j + 5);
      int s6 = __builtin_amdgcn_readlane(sv, j + 6);
      int s7 = __builtin_amdgcn_readlane(sv, j + 7);
      float ew0 = el1[(size_t)s0 * 32 + slot];
      float ew1 = el1[(size_t)s1 * 32 + slot];
      float ew2 = el1[(size_t)s2 * 32 + slot];
      float ew3 = el1[(size_t)s3 * 32 + slot];
      float ew4 = el1[(size_t)s4 * 32 + slot];
      float ew5 = el1[(size_t)s5 * 32 + slot];
      float ew6 = el1[(size_t)s6 * 32 + slot];
      float ew7 = el1[(size_t)s7 * 32 + slot];
      const __half* x0 = xh + (size_t)(s0 * 4 + t) * 32 + hf * 16;
      const __half* x1 = xh + (size_t)(s1 * 4 + t) * 32 + hf * 16;
      const __half* x2 = xh + (size_t)(s2 * 4 + t) * 32 + hf * 16;
      const __half* x3 = xh + (size_t)(s3 * 4 + t) * 32 + hf * 16;
      const __half* x4 = xh + (size_t)(s4 * 4 + t) * 32 + hf * 16;
      const __half* x5 = xh + (size_t)(s5 * 4 + t) * 32 + hf * 16;
      const __half* x6 = xh + (size_t)(s6 * 4 + t) * 32 + hf * 16;
      const __half* x7 = xh + (size_t)(s7 * 4 + t) * 32 + hf * 16;
      h8 a0 = *(const h8*)x0, b0 = *(const h8*)(x0 + 8);
      h8 a1 = *(const h8*)x1, b1_ = *(const h8*)(x1 + 8);
      h8 a2 = *(const h8*)x2, b2_ = *(const h8*)(x2 + 8);
      h8 a3 = *(const h8*)x3, b3_ = *(const h8*)(x3 + 8);
      h8 a4 = *(const h8*)x4, b4_ = *(const h8*)(x4 + 8);
      h8 a5 = *(const h8*)x5, b5_ = *(const h8*)(x5 + 8);
      h8 a6 = *(const h8*)x6, b6_ = *(const h8*)(x6 + 8);
      h8 a7 = *(const h8*)x7, b7_ = *(const h8*)(x7 + 8);
#define CONSUME(K, EW, XA, XB)                                    \
      {                                                           \
        float w_ = lrelu_exp(EW + er_i);                          \
        w_ = (j + K < m) ? w_ : 0.f;                              \
        l += w_;                                                  \
        _Pragma("unroll")                                         \
        for (int q = 0; q < 8; ++q) {                             \
          acc[q]     = fmaf(w_, (float)XA[q], acc[q]);            \
          acc[8 + q] = fmaf(w_, (float)XB[q], acc[8 + q]);        \
        }                                                         \
      }
      CONSUME(0, ew0, a0, b0) CONSUME(1, ew1, a1, b1_)
      CONSUME(2, ew2, a2, b2_) CONSUME(3, ew3, a3, b3_)
      CONSUME(4, ew4, a4, b4_) CONSUME(5, ew5, a5, b5_)
      CONSUME(6, ew6, a6, b6_) CONSUME(7, ew7, a7, b7_)
#undef CONSUME
    }
  }
  float inv = (l > 0.f) ? (1.f / l) : 0.f;
  h8 r0, r1;
#pragma unroll
  for (int q = 0; q < 8; ++q) {
    r0[q] = (_Float16)(acc[q] * inv);
    r1[q] = (_Float16)(acc[8 + q] * inv);
  }
  int hh_ = slot & 7;
  __half* op = aggx + (size_t)(n * 4 + t) * 256 + hh_ * 32 + hf * 16;
  *(h8*)op = r0;
  *(h8*)(op + 8) = r1;
}

// ---------------------------------------------------------------------------
// K3: fused mid: h = aggx per-head GEMM (+b1) -> wave-private LDS h-tile
// (C-layout ds_write, A-layout ds_read_b128) -> feat2/el2/er2 GEMM. h never
// touches global (kills 41 MB of traffic + one launch). Both phases are
// throughput GEMM code — safe to fuse (R9's failure was fusing into the
// latency-tuned gather loop).
// ---------------------------------------------------------------------------
__global__ __launch_bounds__(256) void k_mid2(
    const __half* __restrict__ aggx,     // [nt][8][32]
    const __half* __restrict__ W1hp, const float* __restrict__ b1,
    const __half* __restrict__ W2pp,
    __half* __restrict__ feat2h, float* __restrict__ el2, float* __restrict__ er2) {
  __shared__ __half hs[4][16][C1];       // 16 KB, wave-private tiles
  int tid = threadIdx.x;
  int wave = tid >> 6, lane = tid & 63;
  int m = lane & 15, quad = lane >> 4;
  int rowbase = blockIdx.x * 64 + wave * 16;
  const h8* bp1 = (const h8*)W1hp;
  // phase 1: h rows -> LDS (C-layout: out row quad*4+r, col hh*16+m)
#pragma unroll
  for (int hh_ = 0; hh_ < 8; ++hh_) {
    h8 af = *(const h8*)(aggx + (size_t)(rowbase + m) * 256 + hh_ * 32 + quad * 8);
    f32x4 c = {0.f, 0.f, 0.f, 0.f};
    c = __builtin_amdgcn_mfma_f32_16x16x32_f16(af, bp1[hh_ * 64 + lane], c, 0, 0, 0);
    float bv = b1[hh_ * 16 + m];
#pragma unroll
    for (int r = 0; r < 4; ++r)
      hs[wave][quad * 4 + r][hh_ * 16 + m] = __float2half(c[r] + bv);
  }
  // phase 2: LDS h-tile (A-layout reads) -> feat2 + el2/er2
  // same-wave ds ordering: no barrier needed
  const h8* bp2 = (const h8*)W2pp;
  f32x4 cF = {0.f, 0.f, 0.f, 0.f};
  f32x4 cE = {0.f, 0.f, 0.f, 0.f};
#pragma unroll
  for (int ks = 0; ks < 4; ++ks) {
    h8 af = *(const h8*)&hs[wave][m][ks * 32 + quad * 8];
    cF = __builtin_amdgcn_mfma_f32_16x16x32_f16(af, bp2[ks * 64 + lane], cF, 0, 0, 0);
    cE = __builtin_amdgcn_mfma_f32_16x16x32_f16(af, bp2[(4 + ks) * 64 + lane], cE, 0, 0, 0);
  }
#pragma unroll
  for (int r = 0; r < 4; ++r) {
    int orow = rowbase + quad * 4 + r;
    feat2h[(size_t)orow * OUT_F + m] = __float2half(cF[r]);
    if (m == 0) el2[orow] = cE[r];
    if (m == 1) er2[orow] = cE[r];
  }
}

// ---------------------------------------------------------------------------
// K4: layer-2 aggregate, no-routing form. One wave per node; lane owns
// (t = lane>>4, f = lane&15); alpha computed locally; 8-edge batches.
// ---------------------------------------------------------------------------
__global__ __launch_bounds__(256) void k_agg2x(
    const __half* __restrict__ feat2h,   // [nt][16]
    const float* __restrict__ el2, const float* __restrict__ er2,  // [nt]
    const int* __restrict__ cnt, const int* __restrict__ csr96,
    const float* __restrict__ b2, float* __restrict__ out) {
  int tid = threadIdx.x;
  int wv = tid >> 6, lane = tid & 63;
  int n = blockIdx.x * 4 + wv;
  int t = lane >> 4, f = lane & 15;
  float ern = er2[n * 4 + t];
  int deg = cnt[n];
  const int* eb = csr96 + (size_t)n * CAP;
  float acc = 0.f, l = 0.f;
  for (int chunk = 0; chunk < deg; chunk += 64) {
    int m = min(64, deg - chunk);
    int sv = (lane < m) ? eb[chunk + lane] : 0;
    int iters = (m + 7) >> 3;
    for (int g = 0; g < iters; ++g) {
      int j = g * 8;
      int s0 = __builtin_amdgcn_readlane(sv, j + 0);
      int s1 = __builtin_amdgcn_readlane(sv, j + 1);
      int s2 = __builtin_amdgcn_readlane(sv, j + 2);
      int s3 = __builtin_amdgcn_readlane(sv, j + 3);
      int s4 = __builtin_amdgcn_readlane(sv, j + 4);
      int s5 = __builtin_amdgcn_readlane(sv, j + 5);
      int s6 = __builtin_amdgcn_readlane(sv, j + 6);
      int s7 = __builtin_amdgcn_readlane(sv, j + 7);
      float e0 = el2[s0 * 4 + t];
      float e1 = el2[s1 * 4 + t];
      float e2 = el2[s2 * 4 + t];
      float e3 = el2[s3 * 4 + t];
      float e4 = el2[s4 * 4 + t];
      float e5 = el2[s5 * 4 + t];
      float e6 = el2[s6 * 4 + t];
      float e7 = el2[s7 * 4 + t];
      __half f0 = feat2h[(size_t)(s0 * 4 + t) * OUT_F + f];
      __half f1 = feat2h[(size_t)(s1 * 4 + t) * OUT_F + f];
      __half f2 = feat2h[(size_t)(s2 * 4 + t) * OUT_F + f];
      __half f3 = feat2h[(size_t)(s3 * 4 + t) * OUT_F + f];
      __half f4 = feat2h[(size_t)(s4 * 4 + t) * OUT_F + f];
      __half f5 = feat2h[(size_t)(s5 * 4 + t) * OUT_F + f];
      __half f6 = feat2h[(size_t)(s6 * 4 + t) * OUT_F + f];
      __half f7 = feat2h[(size_t)(s7 * 4 + t) * OUT_F + f];
#define CONSUME(K, EW, FV)                                        \
      {                                                           \
        float w_ = lrelu_exp(EW + ern);                           \
        w_ = (j + K < m) ? w_ : 0.f;                              \
        l += w_;                                                  \
        acc = fmaf(w_, __half2float(FV), acc);                    \
      }
      CONSUME(0, e0, f0) CONSUME(1, e1, f1)
      CONSUME(2, e2, f2) CONSUME(3, e3, f3)
      CONSUME(4, e4, f4) CONSUME(5, e5, f5)
      CONSUME(6, e6, f6) CONSUME(7, e7, f7)
#undef CONSUME
    }
  }
  float inv = (l > 0.f) ? (1.f / l) : 0.f;
  out[(size_t)(n * 4 + t) * OUT_F + f] = acc * inv + b2[f];
}

// ---------------------------------------------------------------------------
extern "C" void kernel_launch(void* const* d_in, const int* in_sizes, int n_in,
                              void* d_out, int out_size, void* d_ws, size_t ws_size,
                              hipStream_t stream) {
  const float* x   = (const float*)d_in[0];
  const int*   src = (const int*)d_in[1];
  const int*   dst = (const int*)d_in[2];
  const float* W1  = (const float*)d_in[3];
  const float* al1 = (const float*)d_in[4];
  const float* ar1 = (const float*)d_in[5];
  const float* b1  = (const float*)d_in[6];
  const float* W2  = (const float*)d_in[7];
  const float* al2 = (const float*)d_in[8];
  const float* ar2 = (const float*)d_in[9];
  const float* b2  = (const float*)d_in[10];
  float* out = (float*)d_out;

  // Workspace layout (bytes, 256-aligned chunks), ~63 MB total
  char* w = (char*)d_ws;
  __half* xh     = (__half*)w; w += (size_t)NT * IN_F * 2;      // 5.12 MB
  __half* aggx   = (__half*)w; w += (size_t)NT * 256 * 2;       // 40.96 MB
  __half* feat2h = (__half*)w; w += (size_t)NT * OUT_F * 2;     // 2.56 MB
  float*  el1    = (float*)w;  w += (size_t)NT * H1 * 4;        // 2.56 MB
  float*  er1    = (float*)w;  w += (size_t)NT * H1 * 4;
  float*  el2    = (float*)w;  w += (size_t)NT * 4;             // 0.32 MB
  float*  er2    = (float*)w;  w += (size_t)NT * 4;
  __half* W1hp   = (__half*)w; w += (size_t)8 * 512 * 2;
  __half* W2pp   = (__half*)w; w += (size_t)8 * 512 * 2;
  int* cnt     = (int*)w;      w += (size_t)NN * 4;             // 80 KB
  int* csr96   = (int*)w;      w += (size_t)NN * CAP * 4;       // 7.68 MB

  hipMemsetAsync(cnt, 0, NN * sizeof(int), stream);

  k_front<<<SCAT_BLOCKS + 1 + XCAST_BLOCKS, 256, 0, stream>>>(
      x, W1, al1, ar1, W2, al2, ar2, (const int4*)src, (const int4*)dst,
      cnt, csr96, xh, el1, er1, W1hp, W2pp);
  k_agg1x<<<NN / 4, 256, 0, stream>>>(xh, el1, er1, cnt, csr96, aggx);
  k_mid2<<<NT / 64, 256, 0, stream>>>(aggx, W1hp, b1, W2pp, feat2h, el2, er2);
  k_agg2x<<<NN / 4, 256, 0, stream>>>(feat2h, el2, er2, cnt, csr96, b2, out);
}

// Round 13
// 164.518 us; speedup vs baseline: 1.2403x; 1.0644x over previous
//
#include <hip/hip_runtime.h>
#include <hip/hip_fp16.h>
#include <math.h>

// Problem constants (from reference)
#define NN 20000          // nodes
#define TT 4              // time steps
#define EE 320000         // edges
#define NT (NN*TT)        // 80000 rows
#define H1 8              // heads layer 1
#define C1 128            // heads*f_out layer 1
#define IN_F 32
#define OUT_F 16
#define CAP 96            // bucket capacity; max degree Poisson(16) << 96
#define SCAT_BLOCKS 313   // ceil((EE/4)/256)
#define XCAST_BLOCKS 1250 // NT/64

typedef _Float16 h8 __attribute__((ext_vector_type(8)));
typedef float f32x4 __attribute__((ext_vector_type(4)));

__device__ __forceinline__ float lrelu_exp(float e) {
  e = (e >= 0.f) ? e : 0.2f * e;
  return __expf(e);
}

// ---------------------------------------------------------------------------
// K1 "front": blocks 0..312 = bucket-CSR scatter; block 313 = global weight
// prep (W1hp per-head B-frags + W2pp); blocks 314.. = x cast to fp16 +
// el1/er1 via one ELER MFMA (ELER tile built in LDS: 1 tile, cheap).
// ---------------------------------------------------------------------------
__global__ __launch_bounds__(256) void k_front(
    const float* __restrict__ x, const float* __restrict__ W1,
    const float* __restrict__ al1, const float* __restrict__ ar1,
    const float* __restrict__ W2, const float* __restrict__ al2,
    const float* __restrict__ ar2,
    const int4* __restrict__ src4, const int4* __restrict__ dst4,
    int* __restrict__ cnt, int* __restrict__ csr96,
    __half* __restrict__ xh, float* __restrict__ el1, float* __restrict__ er1,
    __half* __restrict__ W1hp, __half* __restrict__ W2pp) {
  __shared__ h8 ELERs[64];               // 1 KB, xcast branch only
  int b = blockIdx.x;
  int tid = threadIdx.x;
  if (b < SCAT_BLOCKS) {
    int e4 = b * 256 + tid;
    if (e4 < EE / 4) {
      int4 s = src4[e4];
      int4 d = dst4[e4];
      int p0 = atomicAdd(&cnt[d.x], 1); csr96[d.x * CAP + p0] = s.x;
      int p1 = atomicAdd(&cnt[d.y], 1); csr96[d.y * CAP + p1] = s.y;
      int p2 = atomicAdd(&cnt[d.z], 1); csr96[d.z * CAP + p2] = s.z;
      int p3 = atomicAdd(&cnt[d.w], 1); csr96[d.w * CAP + p3] = s.w;
    }
    return;
  }
  if (b == SCAT_BLOCKS) {
    // W1hp: 8 per-head B-frag tiles, B[k][n] with n=lane&15, k=(lane>>4)*8+j
    for (int idx = tid; idx < 8 * 512; idx += 256) {
      int tile = idx >> 9;
      int rem = idx & 511;
      int lane = rem >> 3, j = rem & 7;
      int k = (lane >> 4) * 8 + j;
      int n = lane & 15;
      W1hp[idx] = __float2half(W1[k * C1 + tile * 16 + n]);
    }
    // W2pp: 4 feat k-step tiles + 4 [Wl2|Wr2|0] k-step tiles
    for (int idx = tid; idx < 8 * 512; idx += 256) {
      int tile = idx >> 9;
      int rem = idx & 511;
      int lane = rem >> 3, j = rem & 7;
      int ks = tile & 3;
      int k = ks * 32 + (lane >> 4) * 8 + j;
      int n = lane & 15;
      float v = 0.f;
      if (tile < 4) {
        v = W2[k * OUT_F + n];
      } else if (n == 0) {
        float s = 0.f;
        for (int f = 0; f < 16; ++f) s += W2[k * OUT_F + f] * al2[f];
        v = s;
      } else if (n == 1) {
        float s = 0.f;
        for (int f = 0; f < 16; ++f) s += W2[k * OUT_F + f] * ar2[f];
        v = s;
      }
      W2pp[idx] = __float2half(v);
    }
    return;
  }
  // ---- xcast + el/er branch ----
  {
    __half* E = (__half*)ELERs;
    for (int idx = tid; idx < 512; idx += 256) {
      int lane = idx >> 3, j = idx & 7;
      int k = (lane >> 4) * 8 + j;
      int n = lane & 15;
      int hh_ = n & 7;
      const float* a = (n < 8) ? al1 : ar1;
      float s = 0.f;
      for (int f = 0; f < 16; ++f) s += W1[k * C1 + hh_ * 16 + f] * a[hh_ * 16 + f];
      E[idx] = __float2half(s);
    }
  }
  __syncthreads();
  int wave = tid >> 6, lane = tid & 63;
  int m = lane & 15, quad = lane >> 4;
  int rowbase = (b - SCAT_BLOCKS - 1) * 64 + wave * 16;
  int row = rowbase + m;
  const float4* xp = (const float4*)(x + row * IN_F + quad * 8);
  float4 a0 = xp[0], a1 = xp[1];
  h8 af;
  af[0] = (_Float16)a0.x; af[1] = (_Float16)a0.y;
  af[2] = (_Float16)a0.z; af[3] = (_Float16)a0.w;
  af[4] = (_Float16)a1.x; af[5] = (_Float16)a1.y;
  af[6] = (_Float16)a1.z; af[7] = (_Float16)a1.w;
  *(h8*)(xh + (size_t)row * IN_F + quad * 8) = af;   // fp16 x copy
  {
    h8 bf = ELERs[lane];
    f32x4 c = {0.f, 0.f, 0.f, 0.f};
    c = __builtin_amdgcn_mfma_f32_16x16x32_f16(af, bf, c, 0, 0, 0);
#pragma unroll
    for (int r = 0; r < 4; ++r) {
      int orow = rowbase + quad * 4 + r;
      if (m < 8) el1[orow * H1 + m] = c[r];
      else       er1[orow * H1 + (m - 8)] = c[r];
    }
  }
}

// ---------------------------------------------------------------------------
// K2: layer-1 x-form aggregate (GEMM/sum commuted) — exact R11 tuning:
// 4-edge groups, VGPR ~48, occupancy ~33%. R12's 8-edge variant raised
// VGPR to 84, halved occupancy, and regressed 42->56 µs. DO NOT deepen.
// One wave per node; lane owns slot (t,h)=lane>>1 and 16 channels
// (hf=lane&1). alpha computed LOCALLY per lane — no shfl/LDS in hot loop.
// ---------------------------------------------------------------------------
__global__ __launch_bounds__(256) void k_agg1x(
    const __half* __restrict__ xh,       // [nt][32]
    const float* __restrict__ el1,       // [n][32] = [n][t][8]
    const float* __restrict__ er1,
    const int* __restrict__ cnt, const int* __restrict__ csr96,
    __half* __restrict__ aggx) {         // [nt][8h][32]
  int tid = threadIdx.x;
  int wv = tid >> 6, lane = tid & 63;
  int n = blockIdx.x * 4 + wv;
  int slot = lane >> 1;                  // (t,h): t=slot>>3, h=slot&7
  int t = lane >> 4;                     // == slot>>3
  int hf = lane & 1;
  float er_i = er1[(size_t)n * 32 + slot];
  int deg = cnt[n];
  const int* eb = csr96 + (size_t)n * CAP;
  float acc[16];
#pragma unroll
  for (int k = 0; k < 16; ++k) acc[k] = 0.f;
  float l = 0.f;
  for (int chunk = 0; chunk < deg; chunk += 64) {
    int m = min(64, deg - chunk);
    int sv = (lane < m) ? eb[chunk + lane] : 0;
    int iters = (m + 3) >> 2;
    for (int g = 0; g < iters; ++g) {
      int j = g * 4;
      int s0 = __builtin_amdgcn_readlane(sv, j + 0);
      int s1 = __builtin_amdgcn_readlane(sv, j + 1);
      int s2 = __builtin_amdgcn_readlane(sv, j + 2);
      int s3 = __builtin_amdgcn_readlane(sv, j + 3);
      float ew0 = el1[(size_t)s0 * 32 + slot];
      float ew1 = el1[(size_t)s1 * 32 + slot];
      float ew2 = el1[(size_t)s2 * 32 + slot];
      float ew3 = el1[(size_t)s3 * 32 + slot];
      const __half* x0 = xh + (size_t)(s0 * 4 + t) * 32 + hf * 16;
      const __half* x1 = xh + (size_t)(s1 * 4 + t) * 32 + hf * 16;
      const __half* x2 = xh + (size_t)(s2 * 4 + t) * 32 + hf * 16;
      const __half* x3 = xh + (size_t)(s3 * 4 + t) * 32 + hf * 16;
      h8 a0 = *(const h8*)x0, b0 = *(const h8*)(x0 + 8);
      h8 a1 = *(const h8*)x1, b1_ = *(const h8*)(x1 + 8);
      h8 a2 = *(const h8*)x2, b2_ = *(const h8*)(x2 + 8);
      h8 a3 = *(const h8*)x3, b3_ = *(const h8*)(x3 + 8);
#define CONSUME(K, EW, XA, XB)                                    \
      {                                                           \
        float w_ = lrelu_exp(EW + er_i);                          \
        w_ = (j + K < m) ? w_ : 0.f;                              \
        l += w_;                                                  \
        _Pragma("unroll")                                         \
        for (int q = 0; q < 8; ++q) {                             \
          acc[q]     = fmaf(w_, (float)XA[q], acc[q]);            \
          acc[8 + q] = fmaf(w_, (float)XB[q], acc[8 + q]);        \
        }                                                         \
      }
      CONSUME(0, ew0, a0, b0) CONSUME(1, ew1, a1, b1_)
      CONSUME(2, ew2, a2, b2_) CONSUME(3, ew3, a3, b3_)
#undef CONSUME
    }
  }
  float inv = (l > 0.f) ? (1.f / l) : 0.f;
  h8 r0, r1;
#pragma unroll
  for (int q = 0; q < 8; ++q) {
    r0[q] = (_Float16)(acc[q] * inv);
    r1[q] = (_Float16)(acc[8 + q] * inv);
  }
  int hh_ = slot & 7;
  __half* op = aggx + (size_t)(n * 4 + t) * 256 + hh_ * 32 + hf * 16;
  *(h8*)op = r0;
  *(h8*)(op + 8) = r1;
}

// ---------------------------------------------------------------------------
// K3: fused mid: h = aggx per-head GEMM (+b1) -> wave-private LDS h-tile
// (C-layout ds_write, A-layout ds_read_b128) -> feat2/el2/er2 GEMM. h never
// touches global. Both phases are throughput GEMM code — safe fusion.
// ---------------------------------------------------------------------------
__global__ __launch_bounds__(256) void k_mid2(
    const __half* __restrict__ aggx,     // [nt][8][32]
    const __half* __restrict__ W1hp, const float* __restrict__ b1,
    const __half* __restrict__ W2pp,
    __half* __restrict__ feat2h, float* __restrict__ el2, float* __restrict__ er2) {
  __shared__ __half hs[4][16][C1];       // 16 KB, wave-private tiles
  int tid = threadIdx.x;
  int wave = tid >> 6, lane = tid & 63;
  int m = lane & 15, quad = lane >> 4;
  int rowbase = blockIdx.x * 64 + wave * 16;
  const h8* bp1 = (const h8*)W1hp;
  // phase 1: h rows -> LDS (C-layout: out row quad*4+r, col hh*16+m)
#pragma unroll
  for (int hh_ = 0; hh_ < 8; ++hh_) {
    h8 af = *(const h8*)(aggx + (size_t)(rowbase + m) * 256 + hh_ * 32 + quad * 8);
    f32x4 c = {0.f, 0.f, 0.f, 0.f};
    c = __builtin_amdgcn_mfma_f32_16x16x32_f16(af, bp1[hh_ * 64 + lane], c, 0, 0, 0);
    float bv = b1[hh_ * 16 + m];
#pragma unroll
    for (int r = 0; r < 4; ++r)
      hs[wave][quad * 4 + r][hh_ * 16 + m] = __float2half(c[r] + bv);
  }
  // phase 2: LDS h-tile (A-layout reads) -> feat2 + el2/er2
  // same-wave ds ordering: no barrier needed
  const h8* bp2 = (const h8*)W2pp;
  f32x4 cF = {0.f, 0.f, 0.f, 0.f};
  f32x4 cE = {0.f, 0.f, 0.f, 0.f};
#pragma unroll
  for (int ks = 0; ks < 4; ++ks) {
    h8 af = *(const h8*)&hs[wave][m][ks * 32 + quad * 8];
    cF = __builtin_amdgcn_mfma_f32_16x16x32_f16(af, bp2[ks * 64 + lane], cF, 0, 0, 0);
    cE = __builtin_amdgcn_mfma_f32_16x16x32_f16(af, bp2[(4 + ks) * 64 + lane], cE, 0, 0, 0);
  }
#pragma unroll
  for (int r = 0; r < 4; ++r) {
    int orow = rowbase + quad * 4 + r;
    feat2h[(size_t)orow * OUT_F + m] = __float2half(cF[r]);
    if (m == 0) el2[orow] = cE[r];
    if (m == 1) er2[orow] = cE[r];
  }
}

// ---------------------------------------------------------------------------
// K4: layer-2 aggregate, no-routing form. One wave per node; lane owns
// (t = lane>>4, f = lane&15); alpha computed locally; 8-edge batches
// (cheap per-edge state here: VGPR stays low, unlike agg1x).
// ---------------------------------------------------------------------------
__global__ __launch_bounds__(256) void k_agg2x(
    const __half* __restrict__ feat2h,   // [nt][16]
    const float* __restrict__ el2, const float* __restrict__ er2,  // [nt]
    const int* __restrict__ cnt, const int* __restrict__ csr96,
    const float* __restrict__ b2, float* __restrict__ out) {
  int tid = threadIdx.x;
  int wv = tid >> 6, lane = tid & 63;
  int n = blockIdx.x * 4 + wv;
  int t = lane >> 4, f = lane & 15;
  float ern = er2[n * 4 + t];
  int deg = cnt[n];
  const int* eb = csr96 + (size_t)n * CAP;
  float acc = 0.f, l = 0.f;
  for (int chunk = 0; chunk < deg; chunk += 64) {
    int m = min(64, deg - chunk);
    int sv = (lane < m) ? eb[chunk + lane] : 0;
    int iters = (m + 7) >> 3;
    for (int g = 0; g < iters; ++g) {
      int j = g * 8;
      int s0 = __builtin_amdgcn_readlane(sv, j + 0);
      int s1 = __builtin_amdgcn_readlane(sv, j + 1);
      int s2 = __builtin_amdgcn_readlane(sv, j + 2);
      int s3 = __builtin_amdgcn_readlane(sv, j + 3);
      int s4 = __builtin_amdgcn_readlane(sv, j + 4);
      int s5 = __builtin_amdgcn_readlane(sv, j + 5);
      int s6 = __builtin_amdgcn_readlane(sv, j + 6);
      int s7 = __builtin_amdgcn_readlane(sv, j + 7);
      float e0 = el2[s0 * 4 + t];
      float e1 = el2[s1 * 4 + t];
      float e2 = el2[s2 * 4 + t];
      float e3 = el2[s3 * 4 + t];
      float e4 = el2[s4 * 4 + t];
      float e5 = el2[s5 * 4 + t];
      float e6 = el2[s6 * 4 + t];
      float e7 = el2[s7 * 4 + t];
      __half f0 = feat2h[(size_t)(s0 * 4 + t) * OUT_F + f];
      __half f1 = feat2h[(size_t)(s1 * 4 + t) * OUT_F + f];
      __half f2 = feat2h[(size_t)(s2 * 4 + t) * OUT_F + f];
      __half f3 = feat2h[(size_t)(s3 * 4 + t) * OUT_F + f];
      __half f4 = feat2h[(size_t)(s4 * 4 + t) * OUT_F + f];
      __half f5 = feat2h[(size_t)(s5 * 4 + t) * OUT_F + f];
      __half f6 = feat2h[(size_t)(s6 * 4 + t) * OUT_F + f];
      __half f7 = feat2h[(size_t)(s7 * 4 + t) * OUT_F + f];
#define CONSUME(K, EW, FV)                                        \
      {                                                           \
        float w_ = lrelu_exp(EW + ern);                           \
        w_ = (j + K < m) ? w_ : 0.f;                              \
        l += w_;                                                  \
        acc = fmaf(w_, __half2float(FV), acc);                    \
      }
      CONSUME(0, e0, f0) CONSUME(1, e1, f1)
      CONSUME(2, e2, f2) CONSUME(3, e3, f3)
      CONSUME(4, e4, f4) CONSUME(5, e5, f5)
      CONSUME(6, e6, f6) CONSUME(7, e7, f7)
#undef CONSUME
    }
  }
  float inv = (l > 0.f) ? (1.f / l) : 0.f;
  out[(size_t)(n * 4 + t) * OUT_F + f] = acc * inv + b2[f];
}

// ---------------------------------------------------------------------------
extern "C" void kernel_launch(void* const* d_in, const int* in_sizes, int n_in,
                              void* d_out, int out_size, void* d_ws, size_t ws_size,
                              hipStream_t stream) {
  const float* x   = (const float*)d_in[0];
  const int*   src = (const int*)d_in[1];
  const int*   dst = (const int*)d_in[2];
  const float* W1  = (const float*)d_in[3];
  const float* al1 = (const float*)d_in[4];
  const float* ar1 = (const float*)d_in[5];
  const float* b1  = (const float*)d_in[6];
  const float* W2  = (const float*)d_in[7];
  const float* al2 = (const float*)d_in[8];
  const float* ar2 = (const float*)d_in[9];
  const float* b2  = (const float*)d_in[10];
  float* out = (float*)d_out;

  // Workspace layout (bytes, 256-aligned chunks), ~63 MB total
  char* w = (char*)d_ws;
  __half* xh     = (__half*)w; w += (size_t)NT * IN_F * 2;      // 5.12 MB
  __half* aggx   = (__half*)w; w += (size_t)NT * 256 * 2;       // 40.96 MB
  __half* feat2h = (__half*)w; w += (size_t)NT * OUT_F * 2;     // 2.56 MB
  float*  el1    = (float*)w;  w += (size_t)NT * H1 * 4;        // 2.56 MB
  float*  er1    = (float*)w;  w += (size_t)NT * H1 * 4;
  float*  el2    = (float*)w;  w += (size_t)NT * 4;             // 0.32 MB
  float*  er2    = (float*)w;  w += (size_t)NT * 4;
  __half* W1hp   = (__half*)w; w += (size_t)8 * 512 * 2;
  __half* W2pp   = (__half*)w; w += (size_t)8 * 512 * 2;
  int* cnt     = (int*)w;      w += (size_t)NN * 4;             // 80 KB
  int* csr96   = (int*)w;      w += (size_t)NN * CAP * 4;       // 7.68 MB

  hipMemsetAsync(cnt, 0, NN * sizeof(int), stream);

  k_front<<<SCAT_BLOCKS + 1 + XCAST_BLOCKS, 256, 0, stream>>>(
      x, W1, al1, ar1, W2, al2, ar2, (const int4*)src, (const int4*)dst,
      cnt, csr96, xh, el1, er1, W1hp, W2pp);
  k_agg1x<<<NN / 4, 256, 0, stream>>>(xh, el1, er1, cnt, csr96, aggx);
  k_mid2<<<NT / 64, 256, 0, stream>>>(aggx, W1hp, b1, W2pp, feat2h, el2, er2);
  k_agg2x<<<NN / 4, 256, 0, stream>>>(feat2h, el2, er2, cnt, csr96, b2, out);
}